// Round 5
// baseline (897.600 us; speedup 1.0000x reference)
//
#include <hip/hip_runtime.h>
#include <hip/hip_bf16.h>
#include <hip/hip_cooperative_groups.h>

namespace cg = cooperative_groups;

#define NN   4096
#define NE   32768
#define NB   32
#define GRID 256
#define TPB  256
#define NCACHE 160

typedef __attribute__((ext_vector_type(8))) short short8;
typedef __attribute__((ext_vector_type(4))) float f4;

__device__ __forceinline__ float sigf(float x) { return 1.0f / (1.0f + __expf(-x)); }

struct MegaParams {
    const float* x; const float* edge_attr; const int* edge_idx; const int* batch_map;
    const float* pre_W0; const float* pre_b0; const float* pre_W1; const float* pre_b1;
    const float* pre_W2; const float* pre_b2;
    const float* enn_W1; const float* enn_b1; const float* enn_W2; const float* enn_b2;
    const float* root_W; const float* conv_b;
    const float* gru_Wih; const float* gru_Whh; const float* gru_bih; const float* gru_bhh;
    const float* s2s_Wih; const float* s2s_Whh; const float* s2s_bih; const float* s2s_bhh;
    const float* post_W0; const float* post_b0; const float* post_W1; const float* post_b1;
    const float* post_W2; const float* post_b2; const float* post_W3; const float* post_b3;
    float* outA; float* outB; __hip_bfloat16* P; float* BT; float* agg;
    __hip_bfloat16* W2T;
    int* csr_off; int* fill_ptr; int* cnt_src; int* cnt_dst; float* invdeg;
    int* csr_dst; float* csr_ea; int* bstart; int* bend; float* y;
};

// ---------- mega-kernel phase helpers ----------

__device__ __forceinline__ void ph_w2t(const MegaParams& p, int bid, int t, char* smem) {
    __hip_bfloat16* tile = (__hip_bfloat16*)smem;  // 64*65*2 = 8320 B
    for (int tl = bid; tl < 192; tl += GRID) {
        size_t base = (size_t)tl * 4096;
        for (int i = t; i < 4096; i += TPB) {
            int k = i >> 6, o = i & 63;
            tile[o * 65 + k] = __float2bfloat16(p.enn_W2[base + i]);
        }
        __syncthreads();
        for (int i = t; i < 4096; i += TPB) {
            int o = i >> 6, k = i & 63;
            p.W2T[base + i] = tile[o * 65 + k];
        }
        __syncthreads();
    }
}

__device__ __forceinline__ void ph_premlp(const MegaParams& p, int bid, int t, char* smem) {
    float* xr = (float*)(smem + 16384);
    float* ha = (float*)(smem + 18432);
    float* hb = (float*)(smem + 19456);
    int w = t >> 6, j = t & 63;
    for (int grp = bid; grp < 1024; grp += GRID) {
        int n = grp * 4 + w;
        xr[w * 128 + j] = p.x[(size_t)n * 128 + j];
        xr[w * 128 + 64 + j] = p.x[(size_t)n * 128 + 64 + j];
        float s = p.pre_b0[j];
        #pragma unroll 8
        for (int k = 0; k < 128; ++k) s = fmaf(xr[w * 128 + k], p.pre_W0[k * 64 + j], s);
        ha[w * 64 + j] = fmaxf(s, 0.f);
        s = p.pre_b1[j];
        #pragma unroll 8
        for (int k = 0; k < 64; ++k) s = fmaf(ha[w * 64 + k], p.pre_W1[k * 64 + j], s);
        hb[w * 64 + j] = fmaxf(s, 0.f);
        s = p.pre_b2[j];
        #pragma unroll 8
        for (int k = 0; k < 64; ++k) s = fmaf(hb[w * 64 + k], p.pre_W2[k * 64 + j], s);
        p.outA[(size_t)n * 64 + j] = fmaxf(s, 0.f);
    }
}

__device__ __forceinline__ void ph_scan_blk0(const MegaParams& p, int t) {
    __shared__ int part[TPB];
    int base = t * 16;
    int v[16]; int sum = 0;
    #pragma unroll
    for (int j = 0; j < 16; ++j) { v[j] = p.cnt_src[base + j]; sum += v[j]; }
    part[t] = sum;
    __syncthreads();
    for (int off = 1; off < TPB; off <<= 1) {
        int x = (t >= off) ? part[t - off] : 0;
        __syncthreads();
        part[t] += x;
        __syncthreads();
    }
    int excl = part[t] - sum;
    #pragma unroll
    for (int j = 0; j < 16; ++j) {
        p.csr_off[base + j] = excl; p.fill_ptr[base + j] = excl; excl += v[j];
    }
    if (t == TPB - 1) p.csr_off[NN] = part[TPB - 1];
}

__device__ __forceinline__ void ph_gemmP(const MegaParams& p, const float* cur,
                                         const __hip_bfloat16* W2T_l, int bid, int t,
                                         char* smem) {
    __hip_bfloat16* A = (__hip_bfloat16*)smem;  // [64][72]
    int wave = t >> 6, lane = t & 63;
    int laneM = lane & 15, quad = lane >> 4;
    for (int job = bid; job < 512; job += GRID) {
        int mtile = job >> 3, gchunk = job & 7;
        const float* Ain = cur + (size_t)mtile * 64 * 64;
        for (int i = t; i < 4096; i += TPB)
            A[(i >> 6) * 72 + (i & 63)] = __float2bfloat16(Ain[i]);
        __syncthreads();
        int arow = wave * 16 + laneM;
        short8 a0 = *(const short8*)&A[arow * 72 + quad * 8];
        short8 a1 = *(const short8*)&A[arow * 72 + 32 + quad * 8];
        #pragma unroll
        for (int gg = 0; gg < 8; ++gg) {
            int g = gchunk * 8 + gg;
            const __hip_bfloat16* Bt = W2T_l + (size_t)g * 4096;  // [o][k]
            #pragma unroll
            for (int sub = 0; sub < 4; ++sub) {
                int o0 = sub * 16;
                short8 b0v = *(const short8*)(Bt + (o0 + laneM) * 64 + quad * 8);
                short8 b1v = *(const short8*)(Bt + (o0 + laneM) * 64 + 32 + quad * 8);
                f4 acc = {0.f, 0.f, 0.f, 0.f};
                acc = __builtin_amdgcn_mfma_f32_16x16x32_bf16(a0, b0v, acc, 0, 0, 0);
                acc = __builtin_amdgcn_mfma_f32_16x16x32_bf16(a1, b1v, acc, 0, 0, 0);
                int rowg = mtile * 64 + wave * 16 + quad * 4;   // D: row=(lane>>4)*4+r
                int col = g * 64 + o0 + laneM;                  // D: col=lane&15
                #pragma unroll
                for (int r = 0; r < 4; ++r)
                    p.P[(size_t)(rowg + r) * 4096 + col] = __float2bfloat16(acc[r]);
            }
        }
        __syncthreads();
    }
}

__device__ __forceinline__ void ph_bterm(const MegaParams& p, const float* cur,
                                         const float* b2l, int bid, int t, char* smem) {
    float* sh = (float*)(smem + 12288);
    int w = t >> 6, j = t & 63;
    for (int grp = bid; grp < 1024; grp += GRID) {
        int n = grp * 4 + w;
        sh[w * 64 + j] = cur[(size_t)n * 64 + j];
        p.agg[(size_t)n * 64 + j] = 0.f;
        float s = 0.f;
        #pragma unroll 8
        for (int k = 0; k < 64; ++k) s = fmaf(sh[w * 64 + k], b2l[k * 64 + j], s);
        p.BT[(size_t)n * 64 + j] = s;
    }
}

#define MSG_CHUNK 128
__device__ __forceinline__ void ph_msg(const MegaParams& p, const float* W1l,
                                       const float* b1l, int bid, int t, char* smem) {
    float* wlds = (float*)smem;  // [128][64] = 32 KB
    int wave = t >> 6, lane = t & 63;
    float w1v = W1l[lane], b1v = b1l[lane];
    for (int grp = bid; grp < 1024; grp += GRID) {
        int n0 = grp * 4;
        int n = n0 + wave;
        int bs = p.csr_off[n0], be = p.csr_off[n0 + 4];
        int ms = p.csr_off[n], me = p.csr_off[n + 1];
        float preg[64];
        const __hip_bfloat16* Pn = p.P + (size_t)n * 4096;
        #pragma unroll
        for (int g = 0; g < 64; ++g) preg[g] = __bfloat162float(Pn[g * 64 + lane]);
        float bt = p.BT[(size_t)n * 64 + lane];
        for (int cs = bs; cs < be; cs += MSG_CHUNK) {
            int ccount = be - cs; if (ccount > MSG_CHUNK) ccount = MSG_CHUNK;
            __syncthreads();
            for (int si = wave; si < ccount; si += 4) {
                float ea = p.csr_ea[cs + si];
                wlds[si * 64 + lane] = fmaxf(fmaf(ea, w1v, b1v), 0.f);
            }
            __syncthreads();
            int i0 = ms > cs ? ms : cs;
            int i1 = me < cs + ccount ? me : cs + ccount;
            for (int i = i0; i < i1; ++i) {
                int si = i - cs;
                int dst = p.csr_dst[i];
                float idg = p.invdeg[dst];
                const float* wr = wlds + si * 64;
                float acc0 = bt, acc1 = 0.f, acc2 = 0.f, acc3 = 0.f;
                #pragma unroll
                for (int g = 0; g < 64; g += 16) {
                    float4 w0 = *(const float4*)(wr + g);
                    float4 w1 = *(const float4*)(wr + g + 4);
                    float4 w2 = *(const float4*)(wr + g + 8);
                    float4 w3 = *(const float4*)(wr + g + 12);
                    acc0 = fmaf(w0.x, preg[g], acc0);
                    acc0 = fmaf(w0.y, preg[g + 1], acc0);
                    acc0 = fmaf(w0.z, preg[g + 2], acc0);
                    acc0 = fmaf(w0.w, preg[g + 3], acc0);
                    acc1 = fmaf(w1.x, preg[g + 4], acc1);
                    acc1 = fmaf(w1.y, preg[g + 5], acc1);
                    acc1 = fmaf(w1.z, preg[g + 6], acc1);
                    acc1 = fmaf(w1.w, preg[g + 7], acc1);
                    acc2 = fmaf(w2.x, preg[g + 8], acc2);
                    acc2 = fmaf(w2.y, preg[g + 9], acc2);
                    acc2 = fmaf(w2.z, preg[g + 10], acc2);
                    acc2 = fmaf(w2.w, preg[g + 11], acc2);
                    acc3 = fmaf(w3.x, preg[g + 12], acc3);
                    acc3 = fmaf(w3.y, preg[g + 13], acc3);
                    acc3 = fmaf(w3.w, preg[g + 15],
                           fmaf(w3.z, preg[g + 14], acc3));
                }
                float acc = (acc0 + acc1) + (acc2 + acc3);
                atomicAdd(&p.agg[(size_t)dst * 64 + lane], acc * idg);
            }
        }
        __syncthreads();
    }
}

__device__ __forceinline__ void ph_gru(const MegaParams& p, const float* cur, float* nxt,
                                       int l, int bid, int t, char* smem) {
    float* sh = (float*)smem;
    float* sc = (float*)(smem + 1024);
    const float* rootW = p.root_W + l * 4096;
    const float* convb = p.conv_b + l * 64;
    const float* Wih = p.gru_Wih + l * 64 * 192;
    const float* Whh = p.gru_Whh + l * 64 * 192;
    const float* bih = p.gru_bih + l * 192;
    const float* bhh = p.gru_bhh + l * 192;
    int w = t >> 6, j = t & 63;
    for (int grp = bid; grp < 1024; grp += GRID) {
        int n = grp * 4 + w;
        float hj = cur[(size_t)n * 64 + j];
        sh[w * 64 + j] = hj;
        float s = p.agg[(size_t)n * 64 + j] + convb[j];
        #pragma unroll 8
        for (int k = 0; k < 64; ++k) s = fmaf(sh[w * 64 + k], rootW[k * 64 + j], s);
        float conv = fmaxf(s, 0.f);
        sc[w * 64 + j] = conv;
        float gir = bih[j], giz = bih[64 + j], gin = bih[128 + j];
        float ghr = bhh[j], ghz = bhh[64 + j], ghn = bhh[128 + j];
        #pragma unroll 4
        for (int k = 0; k < 64; ++k) {
            float c = sc[w * 64 + k], h = sh[w * 64 + k];
            gir = fmaf(c, Wih[k * 192 + j], gir);
            giz = fmaf(c, Wih[k * 192 + 64 + j], giz);
            gin = fmaf(c, Wih[k * 192 + 128 + j], gin);
            ghr = fmaf(h, Whh[k * 192 + j], ghr);
            ghz = fmaf(h, Whh[k * 192 + 64 + j], ghz);
            ghn = fmaf(h, Whh[k * 192 + 128 + j], ghn);
        }
        float r = sigf(gir + ghr);
        float z = sigf(giz + ghz);
        float nn = tanhf(gin + r * ghn);
        nxt[(size_t)n * 64 + j] = (1.f - z) * nn + z * hj;
    }
}

__device__ __forceinline__ void ph_s2s(const MegaParams& p, const float* out,
                                       int bid, int t, char* smem) {
    float* cache = (float*)smem;                    // 160*65
    float* qs    = (float*)(smem + 41600);
    float* hh    = (float*)(smem + 42112);
    float* cc    = (float*)(smem + 42368);
    float* gates = (float*)(smem + 42624);
    float* ebuf  = (float*)(smem + 43648);          // 512
    float* redp  = (float*)(smem + 45696);          // 4*64
    float* tmp64 = (float*)(smem + 46720);
    float* redw4 = (float*)(smem + 46976);
    float* smax  = (float*)(smem + 46992);
    float* sinv  = (float*)(smem + 46996);
    int wave = t >> 6, lane = t & 63;
    int b = bid;
    int s0 = p.bstart[b], e0 = p.bend[b];
    int cnt = e0 - s0;
    if (cnt < 0) cnt = 0;
    if (cnt > 512) cnt = 512;
    int ccnt = cnt < NCACHE ? cnt : NCACHE;
    for (int li = t; li < ccnt * 64; li += TPB) {
        int rowi = li >> 6, d = li & 63;
        cache[rowi * 65 + d] = out[(size_t)(s0 + rowi) * 64 + d];
    }
    if (t < 128) qs[t] = 0.f;
    if (t < 64) { hh[t] = 0.f; cc[t] = 0.f; }
    __syncthreads();
    for (int step = 0; step < 3; ++step) {
        float g = p.s2s_bih[t] + p.s2s_bhh[t];
        #pragma unroll 4
        for (int k = 0; k < 128; ++k) g = fmaf(qs[k], p.s2s_Wih[k * 256 + t], g);
        #pragma unroll 4
        for (int k = 0; k < 64; ++k) g = fmaf(hh[k], p.s2s_Whh[k * 256 + t], g);
        gates[t] = g;
        __syncthreads();
        if (t < 64) {
            float cn = sigf(gates[64 + t]) * cc[t] + sigf(gates[t]) * tanhf(gates[128 + t]);
            cc[t] = cn;
            hh[t] = sigf(gates[192 + t]) * tanhf(cn);
        }
        __syncthreads();
        for (int idx = t; idx < cnt; idx += TPB) {
            float s = 0.f;
            if (idx < NCACHE) {
                const float* row = cache + idx * 65;
                #pragma unroll 8
                for (int d = 0; d < 64; ++d) s = fmaf(row[d], hh[d], s);
            } else {
                const float* row = out + (size_t)(s0 + idx) * 64;
                for (int d = 0; d < 64; ++d) s = fmaf(row[d], hh[d], s);
            }
            ebuf[idx] = s;
        }
        __syncthreads();
        float lm = -3.0e38f;
        for (int i = t; i < cnt; i += TPB) lm = fmaxf(lm, ebuf[i]);
        #pragma unroll
        for (int off = 32; off > 0; off >>= 1) lm = fmaxf(lm, __shfl_down(lm, off, 64));
        if (lane == 0) redw4[wave] = lm;
        __syncthreads();
        if (t == 0)
            *smax = fmaxf(fmaxf(redw4[0], redw4[1]), fmaxf(redw4[2], redw4[3]));
        __syncthreads();
        float m = *smax;
        float ls = 0.f;
        for (int i = t; i < cnt; i += TPB) {
            float av = __expf(ebuf[i] - m);
            ebuf[i] = av;
            ls += av;
        }
        #pragma unroll
        for (int off = 32; off > 0; off >>= 1) ls += __shfl_down(ls, off, 64);
        if (lane == 0) redw4[wave] = ls;
        __syncthreads();
        if (t == 0) {
            float s = redw4[0] + redw4[1] + redw4[2] + redw4[3];
            *sinv = (cnt > 0) ? 1.f / s : 0.f;
        }
        __syncthreads();
        float inv = *sinv;
        float r = 0.f;
        for (int idx = wave; idx < cnt; idx += 4) {
            float v = (idx < NCACHE) ? cache[idx * 65 + lane]
                                     : out[(size_t)(s0 + idx) * 64 + lane];
            r = fmaf(ebuf[idx], v, r);
        }
        redp[wave * 64 + lane] = r;
        __syncthreads();
        if (t < 64) {
            qs[64 + t] = (redp[t] + redp[64 + t] + redp[128 + t] + redp[192 + t]) * inv;
            qs[t] = hh[t];
        }
        __syncthreads();
    }
    if (t < 64) {
        float s = p.post_b0[t];
        #pragma unroll 4
        for (int k = 0; k < 128; ++k) s = fmaf(qs[k], p.post_W0[k * 64 + t], s);
        tmp64[t] = fmaxf(s, 0.f);
    }
    __syncthreads();
    float h1v = 0.f;
    if (t < 64) {
        float s = p.post_b1[t];
        #pragma unroll 4
        for (int k = 0; k < 64; ++k) s = fmaf(tmp64[k], p.post_W1[k * 64 + t], s);
        h1v = fmaxf(s, 0.f);
    }
    __syncthreads();
    if (t < 64) tmp64[t] = h1v;
    __syncthreads();
    if (t < 64) {
        float s = p.post_b2[t];
        #pragma unroll 4
        for (int k = 0; k < 64; ++k) s = fmaf(tmp64[k], p.post_W2[k * 64 + t], s);
        gates[t] = fmaxf(s, 0.f) * p.post_W3[t];
    }
    __syncthreads();
    if (t == 0) {
        float yy = p.post_b3[0];
        for (int k = 0; k < 64; ++k) yy += gates[k];
        p.y[b] = yy;
    }
}

// ---------------- the mega-kernel (GRID=256 -> 1 block/CU co-residency) ----------------

__global__ __launch_bounds__(TPB, 1) void mega(MegaParams p) {
    cg::grid_group grid = cg::this_grid();
    __shared__ __align__(16) char smem[49152];
    int bid = blockIdx.x, t = threadIdx.x;

    // P0: init counters/ranges + W2T transpose + pre-MLP
    for (int i = bid * TPB + t; i < 2 * NN; i += GRID * TPB) {
        if (i < NN) p.cnt_src[i] = 0;
        else p.cnt_dst[i - NN] = 0;
    }
    if (bid == 0 && t < NB) { p.bstart[t] = 0x7FFFFFFF; p.bend[t] = 0; }
    ph_w2t(p, bid, t, smem);
    ph_premlp(p, bid, t, smem);
    grid.sync();

    // P1: degree counts + batch ranges
    for (int e = bid * TPB + t; e < NE; e += GRID * TPB) {
        atomicAdd(&p.cnt_src[p.edge_idx[e]], 1);
        atomicAdd(&p.cnt_dst[p.edge_idx[NE + e]], 1);
    }
    for (int n = bid * TPB + t; n < NN; n += GRID * TPB) {
        int b = p.batch_map[n];
        atomicMin(&p.bstart[b], n);
        atomicMax(&p.bend[b], n + 1);
    }
    grid.sync();

    // P2: prefix scan (block 0) + invdeg
    for (int n = bid * TPB + t; n < NN; n += GRID * TPB) {
        int d = p.cnt_dst[n];
        p.invdeg[n] = 1.0f / (float)(d > 0 ? d : 1);
    }
    if (bid == 0) ph_scan_blk0(p, t);
    grid.sync();

    // P3: CSR fill + gemmP(layer 0) + bterm(layer 0)
    for (int e = bid * TPB + t; e < NE; e += GRID * TPB) {
        int s = p.edge_idx[e];
        int pos = atomicAdd(&p.fill_ptr[s], 1);
        p.csr_dst[pos] = p.edge_idx[NE + e];
        p.csr_ea[pos] = p.edge_attr[e];
    }
    ph_gemmP(p, p.outA, p.W2T, bid, t, smem);
    ph_bterm(p, p.outA, p.enn_b2, bid, t, smem);

    float* bufs[2] = { p.outA, p.outB };
    for (int l = 0; l < 3; ++l) {
        const float* cur = bufs[l & 1];
        float* nxt = bufs[(l + 1) & 1];
        grid.sync();
        ph_msg(p, p.enn_W1 + l * 64, p.enn_b1 + l * 64, bid, t, smem);
        grid.sync();
        ph_gru(p, cur, nxt, l, bid, t, smem);
        if (l < 2) {
            grid.sync();
            ph_gemmP(p, nxt, p.W2T + (size_t)(l + 1) * 64 * 4096, bid, t, smem);
            ph_bterm(p, nxt, p.enn_b2 + (size_t)(l + 1) * 4096, bid, t, smem);
        }
    }
    grid.sync();

    if (bid < NB) ph_s2s(p, p.outB, bid, t, smem);
}

// ================= fallback multi-kernel pipeline (round-3, proven) =================

__global__ __launch_bounds__(256) void k_init(int* cnt_src, int* cnt_dst,
                                              int* bstart, int* bend) {
    int i = blockIdx.x * 256 + threadIdx.x;
    if (i < NN) cnt_src[i] = 0;
    else if (i < 2 * NN) cnt_dst[i - NN] = 0;
    if (i < NB) { bstart[i] = 0x7FFFFFFF; bend[i] = 0; }
}

__global__ void k_count(const int* __restrict__ eidx, const int* __restrict__ bm,
                        int* cnt_src, int* cnt_dst, int* bstart, int* bend) {
    int e = blockIdx.x * 256 + threadIdx.x;
    if (e < NE) {
        atomicAdd(&cnt_src[eidx[e]], 1);
        atomicAdd(&cnt_dst[eidx[NE + e]], 1);
    }
    if (e < NN) {
        int b = bm[e];
        atomicMin(&bstart[b], e);
        atomicMax(&bend[b], e + 1);
    }
}

__global__ __launch_bounds__(1024) void k_scan(const int* __restrict__ cnt_src,
                                               const int* __restrict__ cnt_dst,
                                               int* csr_off, int* fill_ptr, float* invdeg) {
    __shared__ int part[1024];
    int t = threadIdx.x;
    int base = t * 4;
    int v0 = cnt_src[base], v1 = cnt_src[base + 1], v2 = cnt_src[base + 2], v3 = cnt_src[base + 3];
    int mysum = v0 + v1 + v2 + v3;
    part[t] = mysum;
    __syncthreads();
    for (int off = 1; off < 1024; off <<= 1) {
        int x = (t >= off) ? part[t - off] : 0;
        __syncthreads();
        part[t] += x;
        __syncthreads();
    }
    int excl = part[t] - mysum;
    csr_off[base] = excl;     fill_ptr[base] = excl;     excl += v0;
    csr_off[base + 1] = excl; fill_ptr[base + 1] = excl; excl += v1;
    csr_off[base + 2] = excl; fill_ptr[base + 2] = excl; excl += v2;
    csr_off[base + 3] = excl; fill_ptr[base + 3] = excl;
    if (t == 1023) csr_off[NN] = part[1023];
    for (int n = t; n < NN; n += 1024) {
        int d = cnt_dst[n];
        invdeg[n] = 1.0f / (float)(d > 0 ? d : 1);
    }
}

__global__ void k_fill(const int* __restrict__ eidx, const float* __restrict__ ea,
                       int* fill_ptr, int* csr_dst, float* csr_ea) {
    int e = blockIdx.x * 256 + threadIdx.x;
    if (e < NE) {
        int s = eidx[e];
        int pos = atomicAdd(&fill_ptr[s], 1);
        csr_dst[pos] = eidx[NE + e];
        csr_ea[pos] = ea[e];
    }
}

__global__ __launch_bounds__(256) void k_w2t(const float* __restrict__ enn_W2,
                                             __hip_bfloat16* __restrict__ W2T) {
    __shared__ __hip_bfloat16 tile[64 * 65];
    size_t base = (size_t)blockIdx.x * 4096;
    int t = threadIdx.x;
    for (int i = t; i < 4096; i += 256) {
        int k = i >> 6, o = i & 63;
        tile[o * 65 + k] = __float2bfloat16(enn_W2[base + i]);
    }
    __syncthreads();
    for (int i = t; i < 4096; i += 256) {
        int o = i >> 6, k = i & 63;
        W2T[base + i] = tile[o * 65 + k];
    }
}

__global__ __launch_bounds__(256) void k_premlp(const float* __restrict__ x,
        const float* __restrict__ W0, const float* __restrict__ b0,
        const float* __restrict__ W1, const float* __restrict__ b1,
        const float* __restrict__ W2, const float* __restrict__ b2,
        float* __restrict__ out) {
    __shared__ float xr[4][128];
    __shared__ float ha[4][64];
    __shared__ float hb[4][64];
    int t = threadIdx.x, w = t >> 6, j = t & 63;
    int n = blockIdx.x * 4 + w;
    xr[w][j] = x[(size_t)n * 128 + j];
    xr[w][64 + j] = x[(size_t)n * 128 + 64 + j];
    __syncthreads();
    float s = b0[j];
    #pragma unroll 8
    for (int k = 0; k < 128; ++k) s = fmaf(xr[w][k], W0[k * 64 + j], s);
    ha[w][j] = fmaxf(s, 0.f);
    __syncthreads();
    s = b1[j];
    #pragma unroll 8
    for (int k = 0; k < 64; ++k) s = fmaf(ha[w][k], W1[k * 64 + j], s);
    hb[w][j] = fmaxf(s, 0.f);
    __syncthreads();
    s = b2[j];
    #pragma unroll 8
    for (int k = 0; k < 64; ++k) s = fmaf(hb[w][k], W2[k * 64 + j], s);
    out[(size_t)n * 64 + j] = fmaxf(s, 0.f);
}

__global__ __launch_bounds__(256) void k_gemmP(const float* __restrict__ out,
        const __hip_bfloat16* __restrict__ W2T_l, __hip_bfloat16* __restrict__ P) {
    __shared__ __hip_bfloat16 A[64][72];
    int mtile = blockIdx.x, gchunk = blockIdx.y;
    int t = threadIdx.x;
    const float* Ain = out + (size_t)mtile * 64 * 64;
    for (int i = t; i < 4096; i += 256)
        A[i >> 6][i & 63] = __float2bfloat16(Ain[i]);
    __syncthreads();
    int wave = t >> 6, lane = t & 63;
    int laneM = lane & 15, quad = lane >> 4;
    int arow = wave * 16 + laneM;
    short8 a0 = *(const short8*)&A[arow][quad * 8];
    short8 a1 = *(const short8*)&A[arow][32 + quad * 8];
    #pragma unroll
    for (int gg = 0; gg < 8; ++gg) {
        int g = gchunk * 8 + gg;
        const __hip_bfloat16* Bt = W2T_l + (size_t)g * 4096;
        #pragma unroll
        for (int sub = 0; sub < 4; ++sub) {
            int o0 = sub * 16;
            short8 b0v = *(const short8*)(Bt + (o0 + laneM) * 64 + quad * 8);
            short8 b1v = *(const short8*)(Bt + (o0 + laneM) * 64 + 32 + quad * 8);
            f4 acc = {0.f, 0.f, 0.f, 0.f};
            acc = __builtin_amdgcn_mfma_f32_16x16x32_bf16(a0, b0v, acc, 0, 0, 0);
            acc = __builtin_amdgcn_mfma_f32_16x16x32_bf16(a1, b1v, acc, 0, 0, 0);
            int rowg = mtile * 64 + wave * 16 + quad * 4;
            int col = g * 64 + o0 + laneM;
            #pragma unroll
            for (int r = 0; r < 4; ++r)
                P[(size_t)(rowg + r) * 4096 + col] = __float2bfloat16(acc[r]);
        }
    }
}

__global__ __launch_bounds__(256) void k_bterm(const float* __restrict__ out,
        const float* __restrict__ b2l, float* __restrict__ BT, float* __restrict__ agg) {
    __shared__ float sh[4][64];
    int t = threadIdx.x, w = t >> 6, j = t & 63;
    int n = blockIdx.x * 4 + w;
    sh[w][j] = out[(size_t)n * 64 + j];
    agg[(size_t)n * 64 + j] = 0.f;
    __syncthreads();
    float s = 0.f;
    #pragma unroll 8
    for (int k = 0; k < 64; ++k) s = fmaf(sh[w][k], b2l[k * 64 + j], s);
    BT[(size_t)n * 64 + j] = s;
}

__global__ __launch_bounds__(256, 2) void k_msg(const __hip_bfloat16* __restrict__ P,
        const float* __restrict__ BT, const int* __restrict__ csr_off,
        const int* __restrict__ csr_dst, const float* __restrict__ csr_ea,
        const float* __restrict__ invdeg, const float* __restrict__ W1l,
        const float* __restrict__ b1l, float* __restrict__ agg) {
    __shared__ float wlds[MSG_CHUNK][64];
    int t = threadIdx.x, wave = t >> 6, lane = t & 63;
    int n0 = blockIdx.x * 4;
    int n = n0 + wave;
    int bs = csr_off[n0], be = csr_off[n0 + 4];
    int ms = csr_off[n], me = csr_off[n + 1];
    float w1v = W1l[lane], b1v = b1l[lane];
    float preg[64];
    const __hip_bfloat16* Pn = P + (size_t)n * 4096;
    #pragma unroll
    for (int g = 0; g < 64; ++g) preg[g] = __bfloat162float(Pn[g * 64 + lane]);
    float bt = BT[(size_t)n * 64 + lane];
    for (int cs = bs; cs < be; cs += MSG_CHUNK) {
        int ccount = be - cs; if (ccount > MSG_CHUNK) ccount = MSG_CHUNK;
        __syncthreads();
        for (int si = wave; si < ccount; si += 4) {
            float ea = csr_ea[cs + si];
            wlds[si][lane] = fmaxf(fmaf(ea, w1v, b1v), 0.f);
        }
        __syncthreads();
        int i0 = ms > cs ? ms : cs;
        int i1 = me < cs + ccount ? me : cs + ccount;
        for (int i = i0; i < i1; ++i) {
            int si = i - cs;
            int dst = csr_dst[i];
            float idg = invdeg[dst];
            const float* wr = wlds[si];
            float acc0 = bt, acc1 = 0.f, acc2 = 0.f, acc3 = 0.f;
            #pragma unroll
            for (int g = 0; g < 64; g += 16) {
                float4 w0 = *(const float4*)(wr + g);
                float4 w1 = *(const float4*)(wr + g + 4);
                float4 w2 = *(const float4*)(wr + g + 8);
                float4 w3 = *(const float4*)(wr + g + 12);
                acc0 = fmaf(w0.x, preg[g], acc0);
                acc0 = fmaf(w0.y, preg[g + 1], acc0);
                acc0 = fmaf(w0.z, preg[g + 2], acc0);
                acc0 = fmaf(w0.w, preg[g + 3], acc0);
                acc1 = fmaf(w1.x, preg[g + 4], acc1);
                acc1 = fmaf(w1.y, preg[g + 5], acc1);
                acc1 = fmaf(w1.z, preg[g + 6], acc1);
                acc1 = fmaf(w1.w, preg[g + 7], acc1);
                acc2 = fmaf(w2.x, preg[g + 8], acc2);
                acc2 = fmaf(w2.y, preg[g + 9], acc2);
                acc2 = fmaf(w2.z, preg[g + 10], acc2);
                acc2 = fmaf(w2.w, preg[g + 11], acc2);
                acc3 = fmaf(w3.x, preg[g + 12], acc3);
                acc3 = fmaf(w3.y, preg[g + 13], acc3);
                acc3 = fmaf(w3.z, preg[g + 14], acc3);
                acc3 = fmaf(w3.w, preg[g + 15], acc3);
            }
            float acc = (acc0 + acc1) + (acc2 + acc3);
            atomicAdd(&agg[(size_t)dst * 64 + lane], acc * idg);
        }
    }
}

__global__ __launch_bounds__(256) void k_gru(const float* __restrict__ out,
        const float* __restrict__ agg, const float* __restrict__ rootW,
        const float* __restrict__ convb, const float* __restrict__ Wih,
        const float* __restrict__ Whh, const float* __restrict__ bih,
        const float* __restrict__ bhh, float* __restrict__ outn) {
    __shared__ float sh[4][64], sc[4][64];
    int t = threadIdx.x, w = t >> 6, j = t & 63;
    int n = blockIdx.x * 4 + w;
    float hj = out[(size_t)n * 64 + j];
    sh[w][j] = hj;
    __syncthreads();
    float s = agg[(size_t)n * 64 + j] + convb[j];
    #pragma unroll 8
    for (int k = 0; k < 64; ++k) s = fmaf(sh[w][k], rootW[k * 64 + j], s);
    float conv = fmaxf(s, 0.f);
    sc[w][j] = conv;
    __syncthreads();
    float gir = bih[j], giz = bih[64 + j], gin = bih[128 + j];
    float ghr = bhh[j], ghz = bhh[64 + j], ghn = bhh[128 + j];
    #pragma unroll 4
    for (int k = 0; k < 64; ++k) {
        float c = sc[w][k], h = sh[w][k];
        gir = fmaf(c, Wih[k * 192 + j], gir);
        giz = fmaf(c, Wih[k * 192 + 64 + j], giz);
        gin = fmaf(c, Wih[k * 192 + 128 + j], gin);
        ghr = fmaf(h, Whh[k * 192 + j], ghr);
        ghz = fmaf(h, Whh[k * 192 + 64 + j], ghz);
        ghn = fmaf(h, Whh[k * 192 + 128 + j], ghn);
    }
    float r = sigf(gir + ghr);
    float z = sigf(giz + ghz);
    float nn = tanhf(gin + r * ghn);
    outn[(size_t)n * 64 + j] = (1.f - z) * nn + z * hj;
}

__global__ __launch_bounds__(1024) void k_s2s_post(const float* __restrict__ out,
        const int* __restrict__ bstart, const int* __restrict__ bend,
        const float* __restrict__ Wih, const float* __restrict__ Whh,
        const float* __restrict__ bih, const float* __restrict__ bhh,
        const float* __restrict__ pW0, const float* __restrict__ pb0,
        const float* __restrict__ pW1, const float* __restrict__ pb1,
        const float* __restrict__ pW2, const float* __restrict__ pb2,
        const float* __restrict__ pW3, const float* __restrict__ pb3,
        float* __restrict__ y) {
    __shared__ float cache[192 * 65];
    __shared__ float qs[128], hh[64], cc[64], gates[256];
    __shared__ float ebuf[1024];
    __shared__ float redbuf[1024];
    __shared__ float redw[16];
    __shared__ float smax, sinv;
    __shared__ float tmp64[64];
    int t = threadIdx.x, wave = t >> 6, lane = t & 63;
    int b = blockIdx.x;
    int s0 = bstart[b], e0 = bend[b];
    int cnt = e0 - s0;
    if (cnt < 0) cnt = 0;
    if (cnt > 1024) cnt = 1024;
    int ccnt = cnt < 192 ? cnt : 192;
    for (int li = t; li < ccnt * 64; li += 1024) {
        int rowi = li >> 6, d = li & 63;
        cache[rowi * 65 + d] = out[(size_t)(s0 + rowi) * 64 + d];
    }
    int g = t & 255, seg = t >> 8;
    const float* wp;
    int kcnt;
    if (seg == 0)      { wp = Wih + g;             kcnt = 64; }
    else if (seg == 1) { wp = Wih + 64 * 256 + g;  kcnt = 64; }
    else if (seg == 2) { wp = Whh + g;             kcnt = 32; }
    else               { wp = Whh + 32 * 256 + g;  kcnt = 32; }
    float wreg[64];
    #pragma unroll
    for (int j = 0; j < 64; ++j)
        wreg[j] = (j < kcnt) ? wp[(size_t)j * 256] : 0.f;
    if (t < 128) qs[t] = 0.f;
    if (t < 64) { hh[t] = 0.f; cc[t] = 0.f; }
    __syncthreads();
    for (int step = 0; step < 3; ++step) {
        const float* vsrc = (seg == 0) ? qs : (seg == 1) ? qs + 64
                          : (seg == 2) ? hh : hh + 32;
        float partial = 0.f;
        #pragma unroll
        for (int j = 0; j < 64; ++j)
            if (j < kcnt) partial = fmaf(vsrc[j], wreg[j], partial);
        redbuf[seg * 256 + g] = partial;
        __syncthreads();
        if (t < 256)
            gates[t] = bih[t] + bhh[t] + redbuf[t] + redbuf[256 + t]
                     + redbuf[512 + t] + redbuf[768 + t];
        __syncthreads();
        if (t < 64) {
            float cn = sigf(gates[64 + t]) * cc[t] + sigf(gates[t]) * tanhf(gates[128 + t]);
            cc[t] = cn;
            hh[t] = sigf(gates[192 + t]) * tanhf(cn);
        }
        __syncthreads();
        for (int idx = t; idx < cnt; idx += 1024) {
            float s = 0.f;
            if (idx < 192) {
                const float* row = cache + idx * 65;
                #pragma unroll 8
                for (int d = 0; d < 64; ++d) s = fmaf(row[d], hh[d], s);
            } else {
                const float* row = out + (size_t)(s0 + idx) * 64;
                for (int d = 0; d < 64; ++d) s = fmaf(row[d], hh[d], s);
            }
            ebuf[idx] = s;
        }
        __syncthreads();
        float lm = (t < cnt) ? ebuf[t] : -3.0e38f;
        #pragma unroll
        for (int off = 32; off > 0; off >>= 1) lm = fmaxf(lm, __shfl_down(lm, off, 64));
        if (lane == 0) redw[wave] = lm;
        __syncthreads();
        if (t == 0) {
            float m = redw[0];
            #pragma unroll
            for (int w2 = 1; w2 < 16; ++w2) m = fmaxf(m, redw[w2]);
            smax = m;
        }
        __syncthreads();
        float m = smax;
        float av = 0.f;
        if (t < cnt) {
            av = __expf(ebuf[t] - m);
            ebuf[t] = av;
        }
        float ls = av;
        #pragma unroll
        for (int off = 32; off > 0; off >>= 1) ls += __shfl_down(ls, off, 64);
        if (lane == 0) redw[wave] = ls;
        __syncthreads();
        if (t == 0) {
            float s = 0.f;
            #pragma unroll
            for (int w2 = 0; w2 < 16; ++w2) s += redw[w2];
            sinv = (cnt > 0) ? 1.f / s : 0.f;
        }
        __syncthreads();
        float inv = sinv;
        float r = 0.f;
        for (int idx = wave; idx < cnt; idx += 16) {
            float a = ebuf[idx];
            float v = (idx < 192) ? cache[idx * 65 + lane]
                                  : out[(size_t)(s0 + idx) * 64 + lane];
            r = fmaf(a, v, r);
        }
        redbuf[wave * 64 + lane] = r;
        __syncthreads();
        if (t < 64) {
            float s = 0.f;
            #pragma unroll
            for (int w2 = 0; w2 < 16; ++w2) s += redbuf[w2 * 64 + t];
            qs[64 + t] = s * inv;
            qs[t] = hh[t];
        }
        __syncthreads();
    }
    if (t < 64) {
        float s = pb0[t];
        #pragma unroll 4
        for (int k = 0; k < 128; ++k) s = fmaf(qs[k], pW0[k * 64 + t], s);
        tmp64[t] = fmaxf(s, 0.f);
    }
    __syncthreads();
    float h1v = 0.f;
    if (t < 64) {
        float s = pb1[t];
        #pragma unroll 4
        for (int k = 0; k < 64; ++k) s = fmaf(tmp64[k], pW1[k * 64 + t], s);
        h1v = fmaxf(s, 0.f);
    }
    __syncthreads();
    if (t < 64) tmp64[t] = h1v;
    __syncthreads();
    if (t < 64) {
        float s = pb2[t];
        #pragma unroll 4
        for (int k = 0; k < 64; ++k) s = fmaf(tmp64[k], pW2[k * 64 + t], s);
        gates[t] = fmaxf(s, 0.f) * pW3[t];
    }
    __syncthreads();
    if (t == 0) {
        float yy = pb3[0];
        for (int k = 0; k < 64; ++k) yy += gates[k];
        y[b] = yy;
    }
}

// ---------------- host ----------------

extern "C" void kernel_launch(void* const* d_in, const int* in_sizes, int n_in,
                              void* d_out, int out_size, void* d_ws, size_t ws_size,
                              hipStream_t stream) {
    char* wp = (char*)d_ws;
    auto take = [&](size_t bytes) -> char* {
        char* r = wp;
        wp += (bytes + 255) & ~(size_t)255;
        return r;
    };
    MegaParams prm;
    prm.x         = (const float*)d_in[0];
    prm.edge_attr = (const float*)d_in[1];
    prm.edge_idx  = (const int*)d_in[2];
    prm.batch_map = (const int*)d_in[3];
    prm.pre_W0 = (const float*)d_in[4];   prm.pre_b0 = (const float*)d_in[5];
    prm.pre_W1 = (const float*)d_in[6];   prm.pre_b1 = (const float*)d_in[7];
    prm.pre_W2 = (const float*)d_in[8];   prm.pre_b2 = (const float*)d_in[9];
    prm.enn_W1 = (const float*)d_in[10];  prm.enn_b1 = (const float*)d_in[11];
    prm.enn_W2 = (const float*)d_in[12];  prm.enn_b2 = (const float*)d_in[13];
    prm.root_W = (const float*)d_in[14];  prm.conv_b = (const float*)d_in[15];
    prm.gru_Wih = (const float*)d_in[16]; prm.gru_Whh = (const float*)d_in[17];
    prm.gru_bih = (const float*)d_in[18]; prm.gru_bhh = (const float*)d_in[19];
    prm.s2s_Wih = (const float*)d_in[20]; prm.s2s_Whh = (const float*)d_in[21];
    prm.s2s_bih = (const float*)d_in[22]; prm.s2s_bhh = (const float*)d_in[23];
    prm.post_W0 = (const float*)d_in[24]; prm.post_b0 = (const float*)d_in[25];
    prm.post_W1 = (const float*)d_in[26]; prm.post_b1 = (const float*)d_in[27];
    prm.post_W2 = (const float*)d_in[28]; prm.post_b2 = (const float*)d_in[29];
    prm.post_W3 = (const float*)d_in[30]; prm.post_b3 = (const float*)d_in[31];
    prm.y = (float*)d_out;

    prm.outA = (float*)take((size_t)NN * 64 * 4);
    prm.outB = (float*)take((size_t)NN * 64 * 4);
    prm.P    = (__hip_bfloat16*)take((size_t)NN * 4096 * 2);
    prm.BT   = (float*)take((size_t)NN * 64 * 4);
    prm.agg  = (float*)take((size_t)NN * 64 * 4);
    prm.W2T  = (__hip_bfloat16*)take((size_t)3 * 64 * 4096 * 2);
    prm.csr_off  = (int*)take((size_t)(NN + 1) * 4);
    prm.fill_ptr = (int*)take((size_t)NN * 4);
    prm.cnt_src  = (int*)take((size_t)NN * 4);
    prm.cnt_dst  = (int*)take((size_t)NN * 4);
    prm.invdeg   = (float*)take((size_t)NN * 4);
    prm.csr_dst  = (int*)take((size_t)NE * 4);
    prm.csr_ea   = (float*)take((size_t)NE * 4);
    prm.bstart   = (int*)take((size_t)NB * 4);
    prm.bend     = (int*)take((size_t)NB * 4);

    void* args[] = { (void*)&prm };
    hipError_t cerr = hipLaunchCooperativeKernel((const void*)mega, dim3(GRID), dim3(TPB),
                                                 args, 0, stream);
    if (cerr != hipSuccess) {
        (void)hipGetLastError();  // clear sticky error; fall back to multi-kernel path
        k_init<<<(2 * NN) / 256, 256, 0, stream>>>(prm.cnt_src, prm.cnt_dst,
                                                   prm.bstart, prm.bend);
        k_count<<<NE / 256, 256, 0, stream>>>(prm.edge_idx, prm.batch_map, prm.cnt_src,
                                              prm.cnt_dst, prm.bstart, prm.bend);
        k_scan<<<1, 1024, 0, stream>>>(prm.cnt_src, prm.cnt_dst, prm.csr_off,
                                       prm.fill_ptr, prm.invdeg);
        k_fill<<<NE / 256, 256, 0, stream>>>(prm.edge_idx, prm.edge_attr, prm.fill_ptr,
                                             prm.csr_dst, prm.csr_ea);
        k_w2t<<<192, 256, 0, stream>>>(prm.enn_W2, prm.W2T);
        k_premlp<<<NN / 4, 256, 0, stream>>>(prm.x, prm.pre_W0, prm.pre_b0, prm.pre_W1,
                                             prm.pre_b1, prm.pre_W2, prm.pre_b2, prm.outA);
        float* cur = prm.outA;
        float* nxt = prm.outB;
        for (int l = 0; l < 3; ++l) {
            k_gemmP<<<dim3(64, 8), 256, 0, stream>>>(cur, prm.W2T + (size_t)l * 64 * 4096,
                                                     prm.P);
            k_bterm<<<NN / 4, 256, 0, stream>>>(cur, prm.enn_b2 + (size_t)l * 4096,
                                                prm.BT, prm.agg);
            k_msg<<<NN / 4, 256, 0, stream>>>(prm.P, prm.BT, prm.csr_off, prm.csr_dst,
                                              prm.csr_ea, prm.invdeg, prm.enn_W1 + l * 64,
                                              prm.enn_b1 + l * 64, prm.agg);
            k_gru<<<NN / 4, 256, 0, stream>>>(cur, prm.agg, prm.root_W + l * 4096,
                                              prm.conv_b + l * 64,
                                              prm.gru_Wih + l * 64 * 192,
                                              prm.gru_Whh + l * 64 * 192,
                                              prm.gru_bih + l * 192,
                                              prm.gru_bhh + l * 192, nxt);
            float* tmp = cur; cur = nxt; nxt = tmp;
        }
        k_s2s_post<<<NB, 1024, 0, stream>>>(cur, prm.bstart, prm.bend, prm.s2s_Wih,
                                            prm.s2s_Whh, prm.s2s_bih, prm.s2s_bhh,
                                            prm.post_W0, prm.post_b0, prm.post_W1,
                                            prm.post_b1, prm.post_W2, prm.post_b2,
                                            prm.post_W3, prm.post_b3, prm.y);
    }
}

// Round 7
// 384.000 us; speedup vs baseline: 2.3375x; 2.3375x over previous
//
#include <hip/hip_runtime.h>
#include <hip/hip_bf16.h>
#include <string.h>

#define NN   4096
#define NE   32768
#define NB   32

typedef __attribute__((ext_vector_type(8))) short short8;
typedef __attribute__((ext_vector_type(4))) float f4;

__device__ __forceinline__ float sigf(float x) { return 1.0f / (1.0f + __expf(-x)); }
__device__ __forceinline__ float bf2f(short s) {
    union { unsigned u; float f; } x;
    x.u = ((unsigned)(unsigned short)s) << 16;
    return x.f;
}
__device__ __forceinline__ short f2bf(float f) {
    __hip_bfloat16 h = __float2bfloat16(f);
    short s;
    memcpy(&s, &h, sizeof(short));
    return s;
}

// ---------------- k_setup: init + W2T transpose + pre-MLP (independent work) ----------
// blocks 0..31: zero counters, init batch ranges
// blocks 32..223: enn_W2[l][g][k][o] -> W2T[(l*64+g)][o][k] bf16
// blocks 224..1247: pre-MLP (4 nodes per block)
__global__ __launch_bounds__(256) void k_setup(const float* __restrict__ x,
        const float* __restrict__ W0, const float* __restrict__ b0,
        const float* __restrict__ W1, const float* __restrict__ b1,
        const float* __restrict__ W2, const float* __restrict__ b2,
        const float* __restrict__ enn_W2, __hip_bfloat16* __restrict__ W2T,
        float* __restrict__ out, int* cnt_src, int* cnt_dst, int* bstart, int* bend) {
    int bid = blockIdx.x, t = threadIdx.x;
    if (bid < 32) {
        int i = bid * 256 + t;
        if (i < NN) cnt_src[i] = 0;
        else cnt_dst[i - NN] = 0;
        if (i < NB) { bstart[i] = 0x7FFFFFFF; bend[i] = 0; }
    } else if (bid < 224) {
        __shared__ __hip_bfloat16 tile[64 * 65];
        size_t base = (size_t)(bid - 32) * 4096;
        for (int i = t; i < 4096; i += 256) {
            int k = i >> 6, o = i & 63;
            tile[o * 65 + k] = __float2bfloat16(enn_W2[base + i]);
        }
        __syncthreads();
        for (int i = t; i < 4096; i += 256) {
            int o = i >> 6, k = i & 63;
            W2T[base + i] = tile[o * 65 + k];
        }
    } else {
        __shared__ float xr[4][128], ha[4][64], hb[4][64];
        int w = t >> 6, j = t & 63;
        int n = (bid - 224) * 4 + w;
        xr[w][j] = x[(size_t)n * 128 + j];
        xr[w][64 + j] = x[(size_t)n * 128 + 64 + j];
        float s = b0[j];
        #pragma unroll 8
        for (int k = 0; k < 128; ++k) s = fmaf(xr[w][k], W0[k * 64 + j], s);
        ha[w][j] = fmaxf(s, 0.f);
        s = b1[j];
        #pragma unroll 8
        for (int k = 0; k < 64; ++k) s = fmaf(ha[w][k], W1[k * 64 + j], s);
        hb[w][j] = fmaxf(s, 0.f);
        s = b2[j];
        #pragma unroll 8
        for (int k = 0; k < 64; ++k) s = fmaf(hb[w][k], W2[k * 64 + j], s);
        out[(size_t)n * 64 + j] = fmaxf(s, 0.f);
    }
}

// ---------------- k_count: degree counts + batch ranges ----------------
__global__ void k_count(const int* __restrict__ eidx, const int* __restrict__ bm,
                        int* cnt_src, int* cnt_dst, int* bstart, int* bend) {
    int e = blockIdx.x * 256 + threadIdx.x;
    if (e < NE) {
        atomicAdd(&cnt_src[eidx[e]], 1);
        atomicAdd(&cnt_dst[eidx[NE + e]], 1);
    }
    if (e < NN) {
        int b = bm[e];
        atomicMin(&bstart[b], e);
        atomicMax(&bend[b], e + 1);
    }
}

// ---------------- k_scan: exclusive prefix over cnt_src (1 block, 256 thr) ----------
__global__ __launch_bounds__(256) void k_scan(const int* __restrict__ cnt_src,
                                              int* csr_off, int* fill_ptr) {
    __shared__ int part[256];
    int t = threadIdx.x;
    int base = t * 16;
    int v[16]; int sum = 0;
    #pragma unroll
    for (int j = 0; j < 16; ++j) { v[j] = cnt_src[base + j]; sum += v[j]; }
    part[t] = sum;
    __syncthreads();
    for (int off = 1; off < 256; off <<= 1) {
        int x = (t >= off) ? part[t - off] : 0;
        __syncthreads();
        part[t] += x;
        __syncthreads();
    }
    int excl = part[t] - sum;
    #pragma unroll
    for (int j = 0; j < 16; ++j) {
        csr_off[base + j] = excl; fill_ptr[base + j] = excl; excl += v[j];
    }
    if (t == 255) csr_off[NN] = part[255];
}

// ---------------- k_gemmPbt: MFMA P-GEMM + bterm/agg-zero (+ CSR fill on layer 0) ----
// P3 layout: P[n*4096 + (g>>3)*512 + o*8 + (g&7)]  (per-lane contiguous over g%8)
// blocks 0..511: gemm job (mtile = b>>3, gchunk = b&7)
// blocks 512..1535: bterm (BT = out.b2) + zero agg
// blocks 1536..1663 (layer 0 only): CSR fill
__global__ __launch_bounds__(256) void k_gemmPbt(const float* __restrict__ out,
        const __hip_bfloat16* __restrict__ W2T_l, const float* __restrict__ b2l,
        __hip_bfloat16* __restrict__ P, float* __restrict__ BT, float* __restrict__ agg,
        const int* __restrict__ eidx, const float* __restrict__ ea,
        int* fill_ptr, int* csr_dst, float* csr_ea) {
    int bid = blockIdx.x, t = threadIdx.x;
    if (bid < 512) {
        __shared__ __hip_bfloat16 A[64][72];
        int mtile = bid >> 3, gchunk = bid & 7;
        const float* Ain = out + (size_t)mtile * 64 * 64;
        for (int i = t; i < 4096; i += 256)
            A[i >> 6][i & 63] = __float2bfloat16(Ain[i]);
        __syncthreads();
        int wave = t >> 6, lane = t & 63;
        int laneM = lane & 15, quad = lane >> 4;
        int arow = wave * 16 + laneM;
        short8 a0 = *(const short8*)&A[arow][quad * 8];
        short8 a1 = *(const short8*)&A[arow][32 + quad * 8];
        #pragma unroll
        for (int sub = 0; sub < 4; ++sub) {
            int o0 = sub * 16;
            float accs[4][8];
            #pragma unroll
            for (int gg = 0; gg < 8; ++gg) {
                const __hip_bfloat16* Bt = W2T_l + (size_t)(gchunk * 8 + gg) * 4096;
                short8 b0v = *(const short8*)(Bt + (o0 + laneM) * 64 + quad * 8);
                short8 b1v = *(const short8*)(Bt + (o0 + laneM) * 64 + 32 + quad * 8);
                f4 acc = {0.f, 0.f, 0.f, 0.f};
                acc = __builtin_amdgcn_mfma_f32_16x16x32_bf16(a0, b0v, acc, 0, 0, 0);
                acc = __builtin_amdgcn_mfma_f32_16x16x32_bf16(a1, b1v, acc, 0, 0, 0);
                #pragma unroll
                for (int r = 0; r < 4; ++r) accs[r][gg] = acc[r];
            }
            int rowg = mtile * 64 + wave * 16 + quad * 4;   // D row = quad*4+r
            #pragma unroll
            for (int r = 0; r < 4; ++r) {
                short8 sv;
                #pragma unroll
                for (int j = 0; j < 8; ++j)
                    sv[j] = f2bf(accs[r][j]);
                *(short8*)(P + (size_t)(rowg + r) * 4096 + gchunk * 512
                             + (o0 + laneM) * 8) = sv;
            }
        }
    } else if (bid < 1536) {
        __shared__ float sh[4][64];
        int w = t >> 6, j = t & 63;
        int n = (bid - 512) * 4 + w;
        sh[w][j] = out[(size_t)n * 64 + j];
        agg[(size_t)n * 64 + j] = 0.f;
        __syncthreads();
        float s = 0.f;
        #pragma unroll 8
        for (int k = 0; k < 64; ++k) s = fmaf(sh[w][k], b2l[k * 64 + j], s);
        BT[(size_t)n * 64 + j] = s;
    } else {
        int e = (bid - 1536) * 256 + t;
        if (e < NE) {
            int s = eidx[e];
            int pos = atomicAdd(&fill_ptr[s], 1);
            csr_dst[pos] = eidx[NE + e];
            csr_ea[pos] = ea[e];
        }
    }
}

// ---------------- k_msg: per-src-wave message + scatter (P3 layout) ----------------
#define MSG_CHUNK 128
__global__ __launch_bounds__(256, 2) void k_msg(const __hip_bfloat16* __restrict__ P,
        const float* __restrict__ BT, const int* __restrict__ csr_off,
        const int* __restrict__ csr_dst, const float* __restrict__ csr_ea,
        const float* __restrict__ W1l, const float* __restrict__ b1l,
        float* __restrict__ agg) {
    __shared__ float wlds[MSG_CHUNK][64];
    int t = threadIdx.x, wave = t >> 6, lane = t & 63;
    int n0 = blockIdx.x * 4;
    int n = n0 + wave;
    int bs = csr_off[n0], be = csr_off[n0 + 4];
    int ms = csr_off[n], me = csr_off[n + 1];
    float w1v = W1l[lane], b1v = b1l[lane];
    // P3: 8 coalesced dwordx4 loads (lane-contiguous 16B) instead of 64 2B loads
    float preg[64];
    const __hip_bfloat16* Pn = P + (size_t)n * 4096 + lane * 8;
    #pragma unroll
    for (int c = 0; c < 8; ++c) {
        short8 v = *(const short8*)(Pn + c * 512);
        #pragma unroll
        for (int j = 0; j < 8; ++j) preg[c * 8 + j] = bf2f(v[j]);
    }
    float bt = BT[(size_t)n * 64 + lane];
    for (int cs = bs; cs < be; cs += MSG_CHUNK) {
        int ccount = be - cs; if (ccount > MSG_CHUNK) ccount = MSG_CHUNK;
        __syncthreads();
        for (int si = wave; si < ccount; si += 4) {
            float eav = csr_ea[cs + si];
            wlds[si][lane] = fmaxf(fmaf(eav, w1v, b1v), 0.f);   // We1 (lane = g)
        }
        __syncthreads();
        int i0 = ms > cs ? ms : cs;
        int i1 = me < cs + ccount ? me : cs + ccount;
        for (int i = i0; i < i1; ++i) {
            int si = i - cs;
            int dst = csr_dst[i];
            const float* wr = wlds[si];
            float acc0 = bt, acc1 = 0.f, acc2 = 0.f, acc3 = 0.f;
            #pragma unroll
            for (int g = 0; g < 64; g += 16) {
                float4 w0 = *(const float4*)(wr + g);
                float4 w1 = *(const float4*)(wr + g + 4);
                float4 w2 = *(const float4*)(wr + g + 8);
                float4 w3 = *(const float4*)(wr + g + 12);
                acc0 = fmaf(w0.x, preg[g], acc0);
                acc0 = fmaf(w0.y, preg[g + 1], acc0);
                acc0 = fmaf(w0.z, preg[g + 2], acc0);
                acc0 = fmaf(w0.w, preg[g + 3], acc0);
                acc1 = fmaf(w1.x, preg[g + 4], acc1);
                acc1 = fmaf(w1.y, preg[g + 5], acc1);
                acc1 = fmaf(w1.z, preg[g + 6], acc1);
                acc1 = fmaf(w1.w, preg[g + 7], acc1);
                acc2 = fmaf(w2.x, preg[g + 8], acc2);
                acc2 = fmaf(w2.y, preg[g + 9], acc2);
                acc2 = fmaf(w2.z, preg[g + 10], acc2);
                acc2 = fmaf(w2.w, preg[g + 11], acc2);
                acc3 = fmaf(w3.x, preg[g + 12], acc3);
                acc3 = fmaf(w3.y, preg[g + 13], acc3);
                acc3 = fmaf(w3.z, preg[g + 14], acc3);
                acc3 = fmaf(w3.w, preg[g + 15], acc3);
            }
            float acc = (acc0 + acc1) + (acc2 + acc3);
            atomicAdd(&agg[(size_t)dst * 64 + lane], acc);   // un-normalized; /deg in GRU
        }
    }
}

// ---------------- k_gru: conv (+deg-normalize) + GRU ----------------
__global__ __launch_bounds__(256) void k_gru(const float* __restrict__ out,
        const float* __restrict__ agg, const int* __restrict__ cnt_dst,
        const float* __restrict__ rootW, const float* __restrict__ convb,
        const float* __restrict__ Wih, const float* __restrict__ Whh,
        const float* __restrict__ bih, const float* __restrict__ bhh,
        float* __restrict__ outn) {
    __shared__ float sh[4][64], sc[4][64];
    int t = threadIdx.x, w = t >> 6, j = t & 63;
    int n = blockIdx.x * 4 + w;
    float hj = out[(size_t)n * 64 + j];
    sh[w][j] = hj;
    int dg = cnt_dst[n];
    float invd = 1.0f / (float)(dg > 0 ? dg : 1);
    __syncthreads();
    float s = agg[(size_t)n * 64 + j] * invd + convb[j];
    #pragma unroll 8
    for (int k = 0; k < 64; ++k) s = fmaf(sh[w][k], rootW[k * 64 + j], s);
    float conv = fmaxf(s, 0.f);
    sc[w][j] = conv;
    __syncthreads();
    float gir = bih[j], giz = bih[64 + j], gin = bih[128 + j];
    float ghr = bhh[j], ghz = bhh[64 + j], ghn = bhh[128 + j];
    #pragma unroll 4
    for (int k = 0; k < 64; ++k) {
        float c = sc[w][k], h = sh[w][k];
        gir = fmaf(c, Wih[k * 192 + j], gir);
        giz = fmaf(c, Wih[k * 192 + 64 + j], giz);
        gin = fmaf(c, Wih[k * 192 + 128 + j], gin);
        ghr = fmaf(h, Whh[k * 192 + j], ghr);
        ghz = fmaf(h, Whh[k * 192 + 64 + j], ghz);
        ghn = fmaf(h, Whh[k * 192 + 128 + j], ghn);
    }
    float r = sigf(gir + ghr);
    float z = sigf(giz + ghz);
    float nn = tanhf(gin + r * ghn);
    outn[(size_t)n * 64 + j] = (1.f - z) * nn + z * hj;
}

// ---------------- Set2Set (3 steps) + post-MLP (round-2 proven version) -------------
__global__ __launch_bounds__(1024) void k_s2s_post(const float* __restrict__ out,
        const int* __restrict__ bstart, const int* __restrict__ bend,
        const float* __restrict__ Wih, const float* __restrict__ Whh,
        const float* __restrict__ bih, const float* __restrict__ bhh,
        const float* __restrict__ pW0, const float* __restrict__ pb0,
        const float* __restrict__ pW1, const float* __restrict__ pb1,
        const float* __restrict__ pW2, const float* __restrict__ pb2,
        const float* __restrict__ pW3, const float* __restrict__ pb3,
        float* __restrict__ y) {
    __shared__ float cache[192 * 65];
    __shared__ float qs[128], hh[64], cc[64], gates[256];
    __shared__ float ebuf[1024];
    __shared__ float redbuf[1024];
    __shared__ float redw[16];
    __shared__ float smax, sinv;
    __shared__ float tmp64[64];
    int t = threadIdx.x, wave = t >> 6, lane = t & 63;
    int b = blockIdx.x;
    int s0 = bstart[b], e0 = bend[b];
    int cnt = e0 - s0;
    if (cnt < 0) cnt = 0;
    if (cnt > 1024) cnt = 1024;
    int ccnt = cnt < 192 ? cnt : 192;
    for (int li = t; li < ccnt * 64; li += 1024) {
        int rowi = li >> 6, d = li & 63;
        cache[rowi * 65 + d] = out[(size_t)(s0 + rowi) * 64 + d];
    }
    int g = t & 255, seg = t >> 8;
    const float* wp;
    int kcnt;
    if (seg == 0)      { wp = Wih + g;             kcnt = 64; }
    else if (seg == 1) { wp = Wih + 64 * 256 + g;  kcnt = 64; }
    else if (seg == 2) { wp = Whh + g;             kcnt = 32; }
    else               { wp = Whh + 32 * 256 + g;  kcnt = 32; }
    float wreg[64];
    #pragma unroll
    for (int j = 0; j < 64; ++j)
        wreg[j] = (j < kcnt) ? wp[(size_t)j * 256] : 0.f;
    if (t < 128) qs[t] = 0.f;
    if (t < 64) { hh[t] = 0.f; cc[t] = 0.f; }
    __syncthreads();
    for (int step = 0; step < 3; ++step) {
        const float* vsrc = (seg == 0) ? qs : (seg == 1) ? qs + 64
                          : (seg == 2) ? hh : hh + 32;
        float partial = 0.f;
        #pragma unroll
        for (int j = 0; j < 64; ++j)
            if (j < kcnt) partial = fmaf(vsrc[j], wreg[j], partial);
        redbuf[seg * 256 + g] = partial;
        __syncthreads();
        if (t < 256)
            gates[t] = bih[t] + bhh[t] + redbuf[t] + redbuf[256 + t]
                     + redbuf[512 + t] + redbuf[768 + t];
        __syncthreads();
        if (t < 64) {
            float cn = sigf(gates[64 + t]) * cc[t] + sigf(gates[t]) * tanhf(gates[128 + t]);
            cc[t] = cn;
            hh[t] = sigf(gates[192 + t]) * tanhf(cn);
        }
        __syncthreads();
        for (int idx = t; idx < cnt; idx += 1024) {
            float s = 0.f;
            if (idx < 192) {
                const float* row = cache + idx * 65;
                #pragma unroll 8
                for (int d = 0; d < 64; ++d) s = fmaf(row[d], hh[d], s);
            } else {
                const float* row = out + (size_t)(s0 + idx) * 64;
                for (int d = 0; d < 64; ++d) s = fmaf(row[d], hh[d], s);
            }
            ebuf[idx] = s;
        }
        __syncthreads();
        float lm = (t < cnt) ? ebuf[t] : -3.0e38f;
        #pragma unroll
        for (int off = 32; off > 0; off >>= 1) lm = fmaxf(lm, __shfl_down(lm, off, 64));
        if (lane == 0) redw[wave] = lm;
        __syncthreads();
        if (t == 0) {
            float m = redw[0];
            #pragma unroll
            for (int w2 = 1; w2 < 16; ++w2) m = fmaxf(m, redw[w2]);
            smax = m;
        }
        __syncthreads();
        float m = smax;
        float av = 0.f;
        if (t < cnt) {
            av = __expf(ebuf[t] - m);
            ebuf[t] = av;
        }
        float ls = av;
        #pragma unroll
        for (int off = 32; off > 0; off >>= 1) ls += __shfl_down(ls, off, 64);
        if (lane == 0) redw[wave] = ls;
        __syncthreads();
        if (t == 0) {
            float s = 0.f;
            #pragma unroll
            for (int w2 = 0; w2 < 16; ++w2) s += redw[w2];
            sinv = (cnt > 0) ? 1.f / s : 0.f;
        }
        __syncthreads();
        float inv = sinv;
        float r = 0.f;
        for (int idx = wave; idx < cnt; idx += 16) {
            float a = ebuf[idx];
            float v = (idx < 192) ? cache[idx * 65 + lane]
                                  : out[(size_t)(s0 + idx) * 64 + lane];
            r = fmaf(a, v, r);
        }
        redbuf[wave * 64 + lane] = r;
        __syncthreads();
        if (t < 64) {
            float s = 0.f;
            #pragma unroll
            for (int w2 = 0; w2 < 16; ++w2) s += redbuf[w2 * 64 + t];
            qs[64 + t] = s * inv;
            qs[t] = hh[t];
        }
        __syncthreads();
    }
    if (t < 64) {
        float s = pb0[t];
        #pragma unroll 4
        for (int k = 0; k < 128; ++k) s = fmaf(qs[k], pW0[k * 64 + t], s);
        tmp64[t] = fmaxf(s, 0.f);
    }
    __syncthreads();
    float h1v = 0.f;
    if (t < 64) {
        float s = pb1[t];
        #pragma unroll 4
        for (int k = 0; k < 64; ++k) s = fmaf(tmp64[k], pW1[k * 64 + t], s);
        h1v = fmaxf(s, 0.f);
    }
    __syncthreads();
    if (t < 64) tmp64[t] = h1v;
    __syncthreads();
    if (t < 64) {
        float s = pb2[t];
        #pragma unroll 4
        for (int k = 0; k < 64; ++k) s = fmaf(tmp64[k], pW2[k * 64 + t], s);
        gates[t] = fmaxf(s, 0.f) * pW3[t];
    }
    __syncthreads();
    if (t == 0) {
        float yy = pb3[0];
        for (int k = 0; k < 64; ++k) yy += gates[k];
        y[b] = yy;
    }
}

// ---------------- host ----------------

extern "C" void kernel_launch(void* const* d_in, const int* in_sizes, int n_in,
                              void* d_out, int out_size, void* d_ws, size_t ws_size,
                              hipStream_t stream) {
    const float* x         = (const float*)d_in[0];
    const float* edge_attr = (const float*)d_in[1];
    const int*   edge_idx  = (const int*)d_in[2];
    const int*   batch_map = (const int*)d_in[3];
    const float* pre_W0 = (const float*)d_in[4];
    const float* pre_b0 = (const float*)d_in[5];
    const float* pre_W1 = (const float*)d_in[6];
    const float* pre_b1 = (const float*)d_in[7];
    const float* pre_W2 = (const float*)d_in[8];
    const float* pre_b2 = (const float*)d_in[9];
    const float* enn_W1 = (const float*)d_in[10];
    const float* enn_b1 = (const float*)d_in[11];
    const float* enn_W2 = (const float*)d_in[12];
    const float* enn_b2 = (const float*)d_in[13];
    const float* root_W = (const float*)d_in[14];
    const float* conv_b = (const float*)d_in[15];
    const float* gru_Wih = (const float*)d_in[16];
    const float* gru_Whh = (const float*)d_in[17];
    const float* gru_bih = (const float*)d_in[18];
    const float* gru_bhh = (const float*)d_in[19];
    const float* s2s_Wih = (const float*)d_in[20];
    const float* s2s_Whh = (const float*)d_in[21];
    const float* s2s_bih = (const float*)d_in[22];
    const float* s2s_bhh = (const float*)d_in[23];
    const float* post_W0 = (const float*)d_in[24];
    const float* post_b0 = (const float*)d_in[25];
    const float* post_W1 = (const float*)d_in[26];
    const float* post_b1 = (const float*)d_in[27];
    const float* post_W2 = (const float*)d_in[28];
    const float* post_b2 = (const float*)d_in[29];
    const float* post_W3 = (const float*)d_in[30];
    const float* post_b3 = (const float*)d_in[31];
    float* yout = (float*)d_out;

    char* wp = (char*)d_ws;
    auto take = [&](size_t bytes) -> char* {
        char* r = wp;
        wp += (bytes + 255) & ~(size_t)255;
        return r;
    };
    float* outA = (float*)take((size_t)NN * 64 * 4);
    float* outB = (float*)take((size_t)NN * 64 * 4);
    __hip_bfloat16* P = (__hip_bfloat16*)take((size_t)NN * 4096 * 2);
    float* BT  = (float*)take((size_t)NN * 64 * 4);
    float* agg = (float*)take((size_t)NN * 64 * 4);
    __hip_bfloat16* W2T = (__hip_bfloat16*)take((size_t)3 * 64 * 4096 * 2);
    int* csr_off  = (int*)take((size_t)(NN + 1) * 4);
    int* fill_ptr = (int*)take((size_t)NN * 4);
    int* cnt_src  = (int*)take((size_t)NN * 4);
    int* cnt_dst  = (int*)take((size_t)NN * 4);
    int* csr_dst  = (int*)take((size_t)NE * 4);
    float* csr_ea = (float*)take((size_t)NE * 4);
    int* bstart   = (int*)take((size_t)NB * 4);
    int* bend     = (int*)take((size_t)NB * 4);

    k_setup<<<1248, 256, 0, stream>>>(x, pre_W0, pre_b0, pre_W1, pre_b1, pre_W2, pre_b2,
                                      enn_W2, W2T, outA, cnt_src, cnt_dst, bstart, bend);
    k_count<<<NE / 256, 256, 0, stream>>>(edge_idx, batch_map, cnt_src, cnt_dst,
                                          bstart, bend);
    k_scan<<<1, 256, 0, stream>>>(cnt_src, csr_off, fill_ptr);

    float* cur = outA;
    float* nxt = outB;
    for (int l = 0; l < 3; ++l) {
        int grid = (l == 0) ? 1664 : 1536;   // layer 0 also does CSR fill
        k_gemmPbt<<<grid, 256, 0, stream>>>(cur, W2T + (size_t)l * 64 * 4096,
                                            enn_b2 + (size_t)l * 4096, P, BT, agg,
                                            edge_idx, edge_attr, fill_ptr, csr_dst, csr_ea);
        k_msg<<<NN / 4, 256, 0, stream>>>(P, BT, csr_off, csr_dst, csr_ea,
                                          enn_W1 + l * 64, enn_b1 + l * 64, agg);
        k_gru<<<NN / 4, 256, 0, stream>>>(cur, agg, cnt_dst, root_W + l * 4096,
                                          conv_b + l * 64, gru_Wih + l * 64 * 192,
                                          gru_Whh + l * 64 * 192, gru_bih + l * 192,
                                          gru_bhh + l * 192, nxt);
        float* tmp = cur; cur = nxt; nxt = tmp;
    }
    k_s2s_post<<<NB, 1024, 0, stream>>>(cur, bstart, bend, s2s_Wih, s2s_Whh, s2s_bih,
                                        s2s_bhh, post_W0, post_b0, post_W1, post_b1,
                                        post_W2, post_b2, post_W3, post_b3, yout);
}

// Round 8
// 369.947 us; speedup vs baseline: 2.4263x; 1.0380x over previous
//
#include <hip/hip_runtime.h>
#include <hip/hip_bf16.h>
#include <string.h>

#define NN   4096
#define NE   32768
#define NB   32
#define BKT  64   // per-src edge bucket capacity (deg ~ Poisson(8); P(>64) ~ 1e-30)

typedef __attribute__((ext_vector_type(8))) short short8;
typedef __attribute__((ext_vector_type(4))) float f4;

__device__ __forceinline__ float sigf(float x) { return 1.0f / (1.0f + __expf(-x)); }
__device__ __forceinline__ float bf2f(short s) {
    union { unsigned u; float f; } x;
    x.u = ((unsigned)(unsigned short)s) << 16;
    return x.f;
}
__device__ __forceinline__ short f2bf(float f) {
    __hip_bfloat16 h = __float2bfloat16(f);
    short s;
    memcpy(&s, &h, sizeof(short));
    return s;
}

// ---------------- k_setup: init + W2T transpose + pre-MLP ----------------
// blocks 0..31: zero counters, init batch ranges
// blocks 32..223: enn_W2[l][g][k][o] -> W2T[(l*64+g)][o][k] bf16
// blocks 224..1247: pre-MLP (4 nodes per block)
__global__ __launch_bounds__(256) void k_setup(const float* __restrict__ x,
        const float* __restrict__ W0, const float* __restrict__ b0,
        const float* __restrict__ W1, const float* __restrict__ b1,
        const float* __restrict__ W2, const float* __restrict__ b2,
        const float* __restrict__ enn_W2, __hip_bfloat16* __restrict__ W2T,
        float* __restrict__ out, int* cnt_src, int* cnt_dst, int* bstart, int* bend) {
    int bid = blockIdx.x, t = threadIdx.x;
    if (bid < 32) {
        int i = bid * 256 + t;
        if (i < NN) cnt_src[i] = 0;
        else cnt_dst[i - NN] = 0;
        if (i < NB) { bstart[i] = 0x7FFFFFFF; bend[i] = 0; }
    } else if (bid < 224) {
        __shared__ __hip_bfloat16 tile[64 * 65];
        size_t base = (size_t)(bid - 32) * 4096;
        for (int i = t; i < 4096; i += 256) {
            int k = i >> 6, o = i & 63;
            tile[o * 65 + k] = __float2bfloat16(enn_W2[base + i]);
        }
        __syncthreads();
        for (int i = t; i < 4096; i += 256) {
            int o = i >> 6, k = i & 63;
            W2T[base + i] = tile[o * 65 + k];
        }
    } else {
        __shared__ float xr[4][128], ha[4][64], hb[4][64];
        int w = t >> 6, j = t & 63;
        int n = (bid - 224) * 4 + w;
        xr[w][j] = x[(size_t)n * 128 + j];
        xr[w][64 + j] = x[(size_t)n * 128 + 64 + j];
        float s = b0[j];
        #pragma unroll 8
        for (int k = 0; k < 128; ++k) s = fmaf(xr[w][k], W0[k * 64 + j], s);
        ha[w][j] = fmaxf(s, 0.f);
        s = b1[j];
        #pragma unroll 8
        for (int k = 0; k < 64; ++k) s = fmaf(ha[w][k], W1[k * 64 + j], s);
        hb[w][j] = fmaxf(s, 0.f);
        s = b2[j];
        #pragma unroll 8
        for (int k = 0; k < 64; ++k) s = fmaf(hb[w][k], W2[k * 64 + j], s);
        out[(size_t)n * 64 + j] = fmaxf(s, 0.f);
    }
}

// ---------------- k_gemmPbt: MFMA P-GEMM + bterm/agg-zero (+ bucket fill on l0) ----
// P3 layout: P[n*4096 + (g>>3)*512 + o*8 + (g&7)]
// blocks 0..511: gemm job (mtile = b>>3, gchunk = b&7)
// blocks 512..1535: bterm (BT = out.b2) + zero agg
// blocks 1536..1663 (layer 0 only): bucket CSR fill + cnt_dst + batch ranges
__global__ __launch_bounds__(256) void k_gemmPbt(const float* __restrict__ out,
        const __hip_bfloat16* __restrict__ W2T_l, const float* __restrict__ b2l,
        __hip_bfloat16* __restrict__ P, float* __restrict__ BT, float* __restrict__ agg,
        const int* __restrict__ eidx, const float* __restrict__ ea,
        const int* __restrict__ bm, int* cnt_src, int* cnt_dst,
        int* csr_dst, float* csr_ea, int* bstart, int* bend) {
    int bid = blockIdx.x, t = threadIdx.x;
    if (bid < 512) {
        __shared__ __hip_bfloat16 A[64][72];
        int mtile = bid >> 3, gchunk = bid & 7;
        const float* Ain = out + (size_t)mtile * 64 * 64;
        for (int i = t; i < 4096; i += 256)
            A[i >> 6][i & 63] = __float2bfloat16(Ain[i]);
        __syncthreads();
        int wave = t >> 6, lane = t & 63;
        int laneM = lane & 15, quad = lane >> 4;
        int arow = wave * 16 + laneM;
        short8 a0 = *(const short8*)&A[arow][quad * 8];
        short8 a1 = *(const short8*)&A[arow][32 + quad * 8];
        #pragma unroll
        for (int sub = 0; sub < 4; ++sub) {
            int o0 = sub * 16;
            float accs[4][8];
            #pragma unroll
            for (int gg = 0; gg < 8; ++gg) {
                const __hip_bfloat16* Bt = W2T_l + (size_t)(gchunk * 8 + gg) * 4096;
                short8 b0v = *(const short8*)(Bt + (o0 + laneM) * 64 + quad * 8);
                short8 b1v = *(const short8*)(Bt + (o0 + laneM) * 64 + 32 + quad * 8);
                f4 acc = {0.f, 0.f, 0.f, 0.f};
                acc = __builtin_amdgcn_mfma_f32_16x16x32_bf16(a0, b0v, acc, 0, 0, 0);
                acc = __builtin_amdgcn_mfma_f32_16x16x32_bf16(a1, b1v, acc, 0, 0, 0);
                #pragma unroll
                for (int r = 0; r < 4; ++r) accs[r][gg] = acc[r];
            }
            int rowg = mtile * 64 + wave * 16 + quad * 4;   // D row = quad*4+r
            #pragma unroll
            for (int r = 0; r < 4; ++r) {
                short8 sv;
                #pragma unroll
                for (int j = 0; j < 8; ++j)
                    sv[j] = f2bf(accs[r][j]);
                *(short8*)(P + (size_t)(rowg + r) * 4096 + gchunk * 512
                             + (o0 + laneM) * 8) = sv;
            }
        }
    } else if (bid < 1536) {
        __shared__ float sh[4][64];
        int w = t >> 6, j = t & 63;
        int n = (bid - 512) * 4 + w;
        sh[w][j] = out[(size_t)n * 64 + j];
        agg[(size_t)n * 64 + j] = 0.f;
        __syncthreads();
        float s = 0.f;
        #pragma unroll 8
        for (int k = 0; k < 64; ++k) s = fmaf(sh[w][k], b2l[k * 64 + j], s);
        BT[(size_t)n * 64 + j] = s;
    } else {
        int e = (bid - 1536) * 256 + t;
        if (e < NE) {
            int s = eidx[e];
            int d = eidx[NE + e];
            int slot = atomicAdd(&cnt_src[s], 1);
            if (slot < BKT) {
                csr_dst[s * BKT + slot] = d;
                csr_ea[s * BKT + slot] = ea[e];
            }
            atomicAdd(&cnt_dst[d], 1);
        }
        if (e < NN) {
            int b = bm[e];
            atomicMin(&bstart[b], e);
            atomicMax(&bend[b], e + 1);
        }
    }
}

// ---------------- k_msg: per-src-wave message + scatter (bucket CSR, barrier-free) --
// Each wave owns one src node's bucket; LDS regions are wave-private so no
// __syncthreads (in-wave LDS write->read ordering via compiler lgkmcnt waits).
#define MSG_CHUNK 32
__global__ __launch_bounds__(256, 2) void k_msg(const __hip_bfloat16* __restrict__ P,
        const float* __restrict__ BT, const int* __restrict__ cnt_src,
        const int* __restrict__ csr_dst, const float* __restrict__ csr_ea,
        const float* __restrict__ W1l, const float* __restrict__ b1l,
        float* __restrict__ agg) {
    __shared__ float wlds[4][MSG_CHUNK][64];   // 32 KB, wave-private rows
    int t = threadIdx.x, wave = t >> 6, lane = t & 63;
    int n = blockIdx.x * 4 + wave;
    int deg = cnt_src[n];
    if (deg > BKT) deg = BKT;
    float w1v = W1l[lane], b1v = b1l[lane];
    // P3: 8 coalesced dwordx4 loads (lane-contiguous 16B)
    float preg[64];
    const __hip_bfloat16* Pn = P + (size_t)n * 4096 + lane * 8;
    #pragma unroll
    for (int c = 0; c < 8; ++c) {
        short8 v = *(const short8*)(Pn + c * 512);
        #pragma unroll
        for (int j = 0; j < 8; ++j) preg[c * 8 + j] = bf2f(v[j]);
    }
    float bt = BT[(size_t)n * 64 + lane];
    const int* bdst = csr_dst + n * BKT;
    const float* bea = csr_ea + n * BKT;
    for (int c0 = 0; c0 < deg; c0 += MSG_CHUNK) {
        int cc = deg - c0; if (cc > MSG_CHUNK) cc = MSG_CHUNK;
        for (int si = 0; si < cc; ++si) {
            float eav = bea[c0 + si];                          // wave-uniform broadcast
            wlds[wave][si][lane] = fmaxf(fmaf(eav, w1v, b1v), 0.f);  // We1 (lane = g)
        }
        for (int i = 0; i < cc; ++i) {
            int dst = bdst[c0 + i];
            const float* wr = wlds[wave][i];
            float acc0 = bt, acc1 = 0.f, acc2 = 0.f, acc3 = 0.f;
            #pragma unroll
            for (int g = 0; g < 64; g += 16) {
                float4 w0 = *(const float4*)(wr + g);
                float4 w1 = *(const float4*)(wr + g + 4);
                float4 w2 = *(const float4*)(wr + g + 8);
                float4 w3 = *(const float4*)(wr + g + 12);
                acc0 = fmaf(w0.x, preg[g], acc0);
                acc0 = fmaf(w0.y, preg[g + 1], acc0);
                acc0 = fmaf(w0.z, preg[g + 2], acc0);
                acc0 = fmaf(w0.w, preg[g + 3], acc0);
                acc1 = fmaf(w1.x, preg[g + 4], acc1);
                acc1 = fmaf(w1.y, preg[g + 5], acc1);
                acc1 = fmaf(w1.z, preg[g + 6], acc1);
                acc1 = fmaf(w1.w, preg[g + 7], acc1);
                acc2 = fmaf(w2.x, preg[g + 8], acc2);
                acc2 = fmaf(w2.y, preg[g + 9], acc2);
                acc2 = fmaf(w2.z, preg[g + 10], acc2);
                acc2 = fmaf(w2.w, preg[g + 11], acc2);
                acc3 = fmaf(w3.x, preg[g + 12], acc3);
                acc3 = fmaf(w3.y, preg[g + 13], acc3);
                acc3 = fmaf(w3.z, preg[g + 14], acc3);
                acc3 = fmaf(w3.w, preg[g + 15], acc3);
            }
            float acc = (acc0 + acc1) + (acc2 + acc3);
            atomicAdd(&agg[(size_t)dst * 64 + lane], acc);   // un-normalized; /deg in GRU
        }
    }
}

// ---------------- k_gru: conv (+deg-normalize) + GRU ----------------
__global__ __launch_bounds__(256) void k_gru(const float* __restrict__ out,
        const float* __restrict__ agg, const int* __restrict__ cnt_dst,
        const float* __restrict__ rootW, const float* __restrict__ convb,
        const float* __restrict__ Wih, const float* __restrict__ Whh,
        const float* __restrict__ bih, const float* __restrict__ bhh,
        float* __restrict__ outn) {
    __shared__ float sh[4][64], sc[4][64];
    int t = threadIdx.x, w = t >> 6, j = t & 63;
    int n = blockIdx.x * 4 + w;
    float hj = out[(size_t)n * 64 + j];
    sh[w][j] = hj;
    int dg = cnt_dst[n];
    float invd = 1.0f / (float)(dg > 0 ? dg : 1);
    __syncthreads();
    float s = agg[(size_t)n * 64 + j] * invd + convb[j];
    #pragma unroll 8
    for (int k = 0; k < 64; ++k) s = fmaf(sh[w][k], rootW[k * 64 + j], s);
    float conv = fmaxf(s, 0.f);
    sc[w][j] = conv;
    __syncthreads();
    float gir = bih[j], giz = bih[64 + j], gin = bih[128 + j];
    float ghr = bhh[j], ghz = bhh[64 + j], ghn = bhh[128 + j];
    #pragma unroll 4
    for (int k = 0; k < 64; ++k) {
        float c = sc[w][k], h = sh[w][k];
        gir = fmaf(c, Wih[k * 192 + j], gir);
        giz = fmaf(c, Wih[k * 192 + 64 + j], giz);
        gin = fmaf(c, Wih[k * 192 + 128 + j], gin);
        ghr = fmaf(h, Whh[k * 192 + j], ghr);
        ghz = fmaf(h, Whh[k * 192 + 64 + j], ghz);
        ghn = fmaf(h, Whh[k * 192 + 128 + j], ghn);
    }
    float r = sigf(gir + ghr);
    float z = sigf(giz + ghz);
    float nn = tanhf(gin + r * ghn);
    outn[(size_t)n * 64 + j] = (1.f - z) * nn + z * hj;
}

// ---------------- Set2Set (3 steps) + post-MLP ----------------
__global__ __launch_bounds__(1024) void k_s2s_post(const float* __restrict__ out,
        const int* __restrict__ bstart, const int* __restrict__ bend,
        const float* __restrict__ Wih, const float* __restrict__ Whh,
        const float* __restrict__ bih, const float* __restrict__ bhh,
        const float* __restrict__ pW0, const float* __restrict__ pb0,
        const float* __restrict__ pW1, const float* __restrict__ pb1,
        const float* __restrict__ pW2, const float* __restrict__ pb2,
        const float* __restrict__ pW3, const float* __restrict__ pb3,
        float* __restrict__ y) {
    __shared__ float cache[192 * 65];
    __shared__ float qs[128], hh[64], cc[64], gates[256];
    __shared__ float ebuf[1024];
    __shared__ float redbuf[1024];
    __shared__ float redw[16];
    __shared__ float smax, sinv;
    __shared__ float tmp64[64];
    int t = threadIdx.x, wave = t >> 6, lane = t & 63;
    int b = blockIdx.x;
    int s0 = bstart[b], e0 = bend[b];
    int cnt = e0 - s0;
    if (cnt < 0) cnt = 0;
    if (cnt > 1024) cnt = 1024;
    int ccnt = cnt < 192 ? cnt : 192;
    for (int li = t; li < ccnt * 64; li += 1024) {
        int rowi = li >> 6, d = li & 63;
        cache[rowi * 65 + d] = out[(size_t)(s0 + rowi) * 64 + d];
    }
    int g = t & 255, seg = t >> 8;
    const float* wp;
    int kcnt;
    if (seg == 0)      { wp = Wih + g;             kcnt = 64; }
    else if (seg == 1) { wp = Wih + 64 * 256 + g;  kcnt = 64; }
    else if (seg == 2) { wp = Whh + g;             kcnt = 32; }
    else               { wp = Whh + 32 * 256 + g;  kcnt = 32; }
    float wreg[64];
    #pragma unroll
    for (int j = 0; j < 64; ++j)
        wreg[j] = (j < kcnt) ? wp[(size_t)j * 256] : 0.f;
    if (t < 128) qs[t] = 0.f;
    if (t < 64) { hh[t] = 0.f; cc[t] = 0.f; }
    __syncthreads();
    for (int step = 0; step < 3; ++step) {
        const float* vsrc = (seg == 0) ? qs : (seg == 1) ? qs + 64
                          : (seg == 2) ? hh : hh + 32;
        float partial = 0.f;
        #pragma unroll
        for (int j = 0; j < 64; ++j)
            if (j < kcnt) partial = fmaf(vsrc[j], wreg[j], partial);
        redbuf[seg * 256 + g] = partial;
        __syncthreads();
        if (t < 256)
            gates[t] = bih[t] + bhh[t] + redbuf[t] + redbuf[256 + t]
                     + redbuf[512 + t] + redbuf[768 + t];
        __syncthreads();
        if (t < 64) {
            float cn = sigf(gates[64 + t]) * cc[t] + sigf(gates[t]) * tanhf(gates[128 + t]);
            cc[t] = cn;
            hh[t] = sigf(gates[192 + t]) * tanhf(cn);
        }
        __syncthreads();
        for (int idx = t; idx < cnt; idx += 1024) {
            float s = 0.f;
            if (idx < 192) {
                const float* row = cache + idx * 65;
                #pragma unroll 8
                for (int d = 0; d < 64; ++d) s = fmaf(row[d], hh[d], s);
            } else {
                const float* row = out + (size_t)(s0 + idx) * 64;
                for (int d = 0; d < 64; ++d) s = fmaf(row[d], hh[d], s);
            }
            ebuf[idx] = s;
        }
        __syncthreads();
        float lm = (t < cnt) ? ebuf[t] : -3.0e38f;
        #pragma unroll
        for (int off = 32; off > 0; off >>= 1) lm = fmaxf(lm, __shfl_down(lm, off, 64));
        if (lane == 0) redw[wave] = lm;
        __syncthreads();
        if (t == 0) {
            float m = redw[0];
            #pragma unroll
            for (int w2 = 1; w2 < 16; ++w2) m = fmaxf(m, redw[w2]);
            smax = m;
        }
        __syncthreads();
        float m = smax;
        float av = 0.f;
        if (t < cnt) {
            av = __expf(ebuf[t] - m);
            ebuf[t] = av;
        }
        float ls = av;
        #pragma unroll
        for (int off = 32; off > 0; off >>= 1) ls += __shfl_down(ls, off, 64);
        if (lane == 0) redw[wave] = ls;
        __syncthreads();
        if (t == 0) {
            float s = 0.f;
            #pragma unroll
            for (int w2 = 0; w2 < 16; ++w2) s += redw[w2];
            sinv = (cnt > 0) ? 1.f / s : 0.f;
        }
        __syncthreads();
        float inv = sinv;
        float r = 0.f;
        for (int idx = wave; idx < cnt; idx += 16) {
            float a = ebuf[idx];
            float v = (idx < 192) ? cache[idx * 65 + lane]
                                  : out[(size_t)(s0 + idx) * 64 + lane];
            r = fmaf(a, v, r);
        }
        redbuf[wave * 64 + lane] = r;
        __syncthreads();
        if (t < 64) {
            float s = 0.f;
            #pragma unroll
            for (int w2 = 0; w2 < 16; ++w2) s += redbuf[w2 * 64 + t];
            qs[64 + t] = s * inv;
            qs[t] = hh[t];
        }
        __syncthreads();
    }
    if (t < 64) {
        float s = pb0[t];
        #pragma unroll 4
        for (int k = 0; k < 128; ++k) s = fmaf(qs[k], pW0[k * 64 + t], s);
        tmp64[t] = fmaxf(s, 0.f);
    }
    __syncthreads();
    float h1v = 0.f;
    if (t < 64) {
        float s = pb1[t];
        #pragma unroll 4
        for (int k = 0; k < 64; ++k) s = fmaf(tmp64[k], pW1[k * 64 + t], s);
        h1v = fmaxf(s, 0.f);
    }
    __syncthreads();
    if (t < 64) tmp64[t] = h1v;
    __syncthreads();
    if (t < 64) {
        float s = pb2[t];
        #pragma unroll 4
        for (int k = 0; k < 64; ++k) s = fmaf(tmp64[k], pW2[k * 64 + t], s);
        gates[t] = fmaxf(s, 0.f) * pW3[t];
    }
    __syncthreads();
    if (t == 0) {
        float yy = pb3[0];
        for (int k = 0; k < 64; ++k) yy += gates[k];
        y[b] = yy;
    }
}

// ---------------- host ----------------

extern "C" void kernel_launch(void* const* d_in, const int* in_sizes, int n_in,
                              void* d_out, int out_size, void* d_ws, size_t ws_size,
                              hipStream_t stream) {
    const float* x         = (const float*)d_in[0];
    const float* edge_attr = (const float*)d_in[1];
    const int*   edge_idx  = (const int*)d_in[2];
    const int*   batch_map = (const int*)d_in[3];
    const float* pre_W0 = (const float*)d_in[4];
    const float* pre_b0 = (const float*)d_in[5];
    const float* pre_W1 = (const float*)d_in[6];
    const float* pre_b1 = (const float*)d_in[7];
    const float* pre_W2 = (const float*)d_in[8];
    const float* pre_b2 = (const float*)d_in[9];
    const float* enn_W1 = (const float*)d_in[10];
    const float* enn_b1 = (const float*)d_in[11];
    const float* enn_W2 = (const float*)d_in[12];
    const float* enn_b2 = (const float*)d_in[13];
    const float* root_W = (const float*)d_in[14];
    const float* conv_b = (const float*)d_in[15];
    const float* gru_Wih = (const float*)d_in[16];
    const float* gru_Whh = (const float*)d_in[17];
    const float* gru_bih = (const float*)d_in[18];
    const float* gru_bhh = (const float*)d_in[19];
    const float* s2s_Wih = (const float*)d_in[20];
    const float* s2s_Whh = (const float*)d_in[21];
    const float* s2s_bih = (const float*)d_in[22];
    const float* s2s_bhh = (const float*)d_in[23];
    const float* post_W0 = (const float*)d_in[24];
    const float* post_b0 = (const float*)d_in[25];
    const float* post_W1 = (const float*)d_in[26];
    const float* post_b1 = (const float*)d_in[27];
    const float* post_W2 = (const float*)d_in[28];
    const float* post_b2 = (const float*)d_in[29];
    const float* post_W3 = (const float*)d_in[30];
    const float* post_b3 = (const float*)d_in[31];
    float* yout = (float*)d_out;

    char* wp = (char*)d_ws;
    auto take = [&](size_t bytes) -> char* {
        char* r = wp;
        wp += (bytes + 255) & ~(size_t)255;
        return r;
    };
    float* outA = (float*)take((size_t)NN * 64 * 4);
    float* outB = (float*)take((size_t)NN * 64 * 4);
    __hip_bfloat16* P = (__hip_bfloat16*)take((size_t)NN * 4096 * 2);
    float* BT  = (float*)take((size_t)NN * 64 * 4);
    float* agg = (float*)take((size_t)NN * 64 * 4);
    __hip_bfloat16* W2T = (__hip_bfloat16*)take((size_t)3 * 64 * 4096 * 2);
    int* cnt_src  = (int*)take((size_t)NN * 4);
    int* cnt_dst  = (int*)take((size_t)NN * 4);
    int* csr_dst  = (int*)take((size_t)NN * BKT * 4);
    float* csr_ea = (float*)take((size_t)NN * BKT * 4);
    int* bstart   = (int*)take((size_t)NB * 4);
    int* bend     = (int*)take((size_t)NB * 4);

    k_setup<<<1248, 256, 0, stream>>>(x, pre_W0, pre_b0, pre_W1, pre_b1, pre_W2, pre_b2,
                                      enn_W2, W2T, outA, cnt_src, cnt_dst, bstart, bend);

    float* cur = outA;
    float* nxt = outB;
    for (int l = 0; l < 3; ++l) {
        int grid = (l == 0) ? 1664 : 1536;   // layer 0 also does bucket CSR fill
        k_gemmPbt<<<grid, 256, 0, stream>>>(cur, W2T + (size_t)l * 64 * 4096,
                                            enn_b2 + (size_t)l * 4096, P, BT, agg,
                                            edge_idx, edge_attr, batch_map,
                                            cnt_src, cnt_dst, csr_dst, csr_ea,
                                            bstart, bend);
        k_msg<<<NN / 4, 256, 0, stream>>>(P, BT, cnt_src, csr_dst, csr_ea,
                                          enn_W1 + l * 64, enn_b1 + l * 64, agg);
        k_gru<<<NN / 4, 256, 0, stream>>>(cur, agg, cnt_dst, root_W + l * 4096,
                                          conv_b + l * 64, gru_Wih + l * 64 * 192,
                                          gru_Whh + l * 64 * 192, gru_bih + l * 192,
                                          gru_bhh + l * 192, nxt);
        float* tmp = cur; cur = nxt; nxt = tmp;
    }
    k_s2s_post<<<NB, 1024, 0, stream>>>(cur, bstart, bend, s2s_Wih, s2s_Whh, s2s_bih,
                                        s2s_bhh, post_W0, post_b0, post_W1, post_b1,
                                        post_W2, post_b2, post_W3, post_b3, yout);
}